// Round 1
// baseline (347.125 us; speedup 1.0000x reference)
//
#include <hip/hip_runtime.h>

// Problem constants (fixed shapes from setup_inputs)
#define Bn   2
#define Cn   64      // Cin == Cout == 64
#define Dd   8
#define Hd   128
#define Wd   128
#define HW   16384   // Hd*Wd
#define DHW  131072  // Dd*Hd*Wd  (= 2^17)
#define NPOS 262144  // Bn*DHW    (= 2^18)
#define NELEM 16777216  // Bn*Cn*DHW

// ---------------------------------------------------------------------------
// Kernel 1: h = head_w @ x  (1x1x1 conv over channels), fused Vp = V_w^T @ h
// One thread per spatial position (b,s). x[:,pos] held in VGPRs; weight reads
// are thread-uniform -> compiler emits s_load (scalar pipe), VALU is pure FMA.
// ---------------------------------------------------------------------------
__global__ __launch_bounds__(256) void k_head(const float* __restrict__ x,
                                              const float* __restrict__ head_w,
                                              const float* __restrict__ V_w,
                                              float* __restrict__ h,
                                              float* __restrict__ Vp)
{
    int p = blockIdx.x * 256 + threadIdx.x;
    if (p >= NPOS) return;
    int b = p >> 17;            // DHW = 2^17
    int s = p & (DHW - 1);

    const float* xb = x + (size_t)b * Cn * DHW + s;
    float xv[Cn];
#pragma unroll
    for (int i = 0; i < Cn; ++i) xv[i] = xb[(size_t)i * DHW];

    float vp0 = 0.f, vp1 = 0.f, vp2 = 0.f;
    float* hb = h + (size_t)b * Cn * DHW + s;

    for (int o = 0; o < Cn; ++o) {
        float a0 = 0.f, a1 = 0.f, a2 = 0.f, a3 = 0.f;
        const float* wr = head_w + o * Cn;   // thread-uniform row
#pragma unroll
        for (int i = 0; i < Cn; i += 4) {
            a0 += wr[i + 0] * xv[i + 0];
            a1 += wr[i + 1] * xv[i + 1];
            a2 += wr[i + 2] * xv[i + 2];
            a3 += wr[i + 3] * xv[i + 3];
        }
        float acc = (a0 + a1) + (a2 + a3);
        hb[(size_t)o * DHW] = acc;
        vp0 += acc * V_w[o * 3 + 0];
        vp1 += acc * V_w[o * 3 + 1];
        vp2 += acc * V_w[o * 3 + 2];
    }

    float* vpb = Vp + (size_t)b * 3 * DHW + s;
    vpb[0]             = vp0;
    vpb[(size_t)DHW]   = vp1;
    vpb[(size_t)2*DHW] = vp2;
}

// ---------------------------------------------------------------------------
// Kernel 2: depthwise 3x3x3 conv (replicate pad) -> Up[r], l2-normalize over
// r, dot with Vp -> UV.  One thread per (b,c,d,h,w) element.
// ---------------------------------------------------------------------------
__global__ __launch_bounds__(256) void k_uv(const float* __restrict__ h,
                                            const float* __restrict__ Vp,
                                            const float* __restrict__ U_w,
                                            float* __restrict__ UV)
{
    size_t e = (size_t)blockIdx.x * 256 + threadIdx.x;
    if (e >= (size_t)NELEM) return;
    int s  = (int)(e & (DHW - 1));
    int bc = (int)(e >> 17);       // b*64 + c
    int b  = bc >> 6;
    int d  = s >> 14;              // HW = 2^14
    int y  = (s >> 7) & (Hd - 1);
    int xw = s & (Wd - 1);

    const float* hb = h + (size_t)bc * DHW;
    float up0 = 0.f, up1 = 0.f, up2 = 0.f;

#pragma unroll
    for (int dk = 0; dk < 3; ++dk) {
        int zd = d + dk - 1; zd = zd < 0 ? 0 : (zd > Dd - 1 ? Dd - 1 : zd);
#pragma unroll
        for (int kh = 0; kh < 3; ++kh) {
            int zy = y + kh - 1; zy = zy < 0 ? 0 : (zy > Hd - 1 ? Hd - 1 : zy);
            const float* row = hb + zd * HW + zy * Wd;
#pragma unroll
            for (int kw = 0; kw < 3; ++kw) {
                int zx = xw + kw - 1; zx = zx < 0 ? 0 : (zx > Wd - 1 ? Wd - 1 : zx);
                float hv = row[zx];
                int k = (dk * 3 + kh) * 3 + kw;   // unfold order (dk,kh,kw)
                up0 += hv * U_w[k * 3 + 0];
                up1 += hv * U_w[k * 3 + 1];
                up2 += hv * U_w[k * 3 + 2];
            }
        }
    }

    float nrm = sqrtf(up0 * up0 + up1 * up1 + up2 * up2);
    float inv = 1.f / (1e-6f + nrm);

    const float* vpb = Vp + (size_t)b * 3 * DHW + s;
    float uv = (up0 * vpb[0] + up1 * vpb[(size_t)DHW] + up2 * vpb[(size_t)2*DHW]) * inv;
    UV[e] = uv;
}

// ---------------------------------------------------------------------------
// Kernel 3: out = tail_w @ UV  (1x1x1 conv over channels)
// ---------------------------------------------------------------------------
__global__ __launch_bounds__(256) void k_tail(const float* __restrict__ UV,
                                              const float* __restrict__ tail_w,
                                              float* __restrict__ out)
{
    int p = blockIdx.x * 256 + threadIdx.x;
    if (p >= NPOS) return;
    int b = p >> 17;
    int s = p & (DHW - 1);

    const float* ub = UV + (size_t)b * Cn * DHW + s;
    float uv[Cn];
#pragma unroll
    for (int i = 0; i < Cn; ++i) uv[i] = ub[(size_t)i * DHW];

    float* ob = out + (size_t)b * Cn * DHW + s;
    for (int o = 0; o < Cn; ++o) {
        float a0 = 0.f, a1 = 0.f, a2 = 0.f, a3 = 0.f;
        const float* wr = tail_w + o * Cn;   // thread-uniform row
#pragma unroll
        for (int i = 0; i < Cn; i += 4) {
            a0 += wr[i + 0] * uv[i + 0];
            a1 += wr[i + 1] * uv[i + 1];
            a2 += wr[i + 2] * uv[i + 2];
            a3 += wr[i + 3] * uv[i + 3];
        }
        ob[(size_t)o * DHW] = (a0 + a1) + (a2 + a3);
    }
}

extern "C" void kernel_launch(void* const* d_in, const int* in_sizes, int n_in,
                              void* d_out, int out_size, void* d_ws, size_t ws_size,
                              hipStream_t stream)
{
    const float* x      = (const float*)d_in[0];   // (2,64,8,128,128)
    const float* head_w = (const float*)d_in[1];   // (64,64)
    const float* tail_w = (const float*)d_in[2];   // (64,64)
    const float* U_w    = (const float*)d_in[3];   // (27,3)
    const float* V_w    = (const float*)d_in[4];   // (64,3)
    float* out = (float*)d_out;

    // Workspace layout: h (64MB) | UV (64MB) | Vp (3MB)
    float* h  = (float*)d_ws;
    float* UV = h + (size_t)NELEM;
    float* Vp = UV + (size_t)NELEM;

    k_head<<<NPOS / 256, 256, 0, stream>>>(x, head_w, V_w, h, Vp);
    k_uv<<<NELEM / 256, 256, 0, stream>>>(h, Vp, U_w, UV);
    k_tail<<<NPOS / 256, 256, 0, stream>>>(UV, tail_w, out);
}

// Round 3
// 319.186 us; speedup vs baseline: 1.0875x; 1.0875x over previous
//
#include <hip/hip_runtime.h>

// Problem constants (fixed shapes from setup_inputs)
#define Bn   2
#define Cn   64      // Cin == Cout == 64
#define Dd   8
#define Hd   128
#define Wd   128
#define HW   16384   // Hd*Wd
#define DHW  131072  // Dd*Hd*Wd  (= 2^17)
#define NPOS 262144  // Bn*DHW    (= 2^18)
#define NELEM 16777216  // Bn*Cn*DHW

// ---------------------------------------------------------------------------
// Kernel 1: h = head_w @ x (1x1x1 conv over channels), fused Vp = V_w^T @ h.
// One thread per position. NO early-return: grid divides exactly, so control
// flow stays uniform and the thread-uniform weight reads scalarize to s_load.
// ---------------------------------------------------------------------------
__global__ __launch_bounds__(256) void k_head(const float* __restrict__ x,
                                              const float* __restrict__ head_w,
                                              const float* __restrict__ V_w,
                                              float* __restrict__ h,
                                              float* __restrict__ Vp)
{
    int p = blockIdx.x * 256 + threadIdx.x;   // grid exact: no guard (uniform CF)
    int b = p >> 17;            // DHW = 2^17
    int s = p & (DHW - 1);

    const float* xb = x + (size_t)b * Cn * DHW + s;
    float xv[Cn];
#pragma unroll
    for (int i = 0; i < Cn; ++i) xv[i] = xb[(size_t)i * DHW];

    float vp0 = 0.f, vp1 = 0.f, vp2 = 0.f;
    float* hb = h + (size_t)b * Cn * DHW + s;

    for (int o = 0; o < Cn; ++o) {
        float a0 = 0.f, a1 = 0.f, a2 = 0.f, a3 = 0.f;
        const float* wr = head_w + o * Cn;   // thread-uniform row -> s_load
#pragma unroll
        for (int i = 0; i < Cn; i += 4) {
            a0 += wr[i + 0] * xv[i + 0];
            a1 += wr[i + 1] * xv[i + 1];
            a2 += wr[i + 2] * xv[i + 2];
            a3 += wr[i + 3] * xv[i + 3];
        }
        float acc = (a0 + a1) + (a2 + a3);
        hb[(size_t)o * DHW] = acc;
        vp0 += acc * V_w[o * 3 + 0];
        vp1 += acc * V_w[o * 3 + 1];
        vp2 += acc * V_w[o * 3 + 2];
    }

    float* vpb = Vp + (size_t)b * 3 * DHW + s;
    vpb[0]             = vp0;
    vpb[(size_t)DHW]   = vp1;
    vpb[(size_t)2*DHW] = vp2;
}

// ---------------------------------------------------------------------------
// Kernel 2: depthwise 3x3x3 conv (replicate pad) -> l2norm over r -> dot Vp.
// Block = (b, c, y-pair). Stage all 8 d-slices x 4 y-rows x 128 of h[b,c]
// into LDS (16 KB) once; each thread emits 8 outputs (one per d). Conv reads
// are LDS stride-1 (2 lanes/bank = free); U_w reads uniform -> s_load.
// ---------------------------------------------------------------------------
__global__ __launch_bounds__(256) void k_uv(const float* __restrict__ h,
                                            const float* __restrict__ Vp,
                                            const float* __restrict__ U_w,
                                            float* __restrict__ UV)
{
    __shared__ float tile[Dd][4][Wd];   // [d][yrow][x], 16 KB

    int blk = blockIdx.x;               // bc*64 + yt
    int yt  = blk & 63;
    int bc  = blk >> 6;                 // b*64 + c
    int b   = bc >> 6;
    int y0  = yt * 2;
    int t   = threadIdx.x;

    const float* hb = h + (size_t)bc * DHW;
#pragma unroll
    for (int it = 0; it < 16; ++it) {   // 4096 floats / 256 threads
        int idx = t + it * 256;
        int d  = idx >> 9;              // 4*128 = 512 per slice
        int yr = (idx >> 7) & 3;
        int xx = idx & 127;
        int zy = y0 - 1 + yr;
        zy = zy < 0 ? 0 : (zy > Hd - 1 ? Hd - 1 : zy);  // replicate clamp
        tile[d][yr][xx] = hb[d * HW + zy * Wd + xx];
    }
    __syncthreads();

    int xx = t & 127;
    int yr = t >> 7;                    // 0..1
    int y  = y0 + yr;
    int xm = xx - 1; if (xm < 0) xm = 0;
    int xp = xx + 1; if (xp > Wd - 1) xp = Wd - 1;

    const float* vpb = Vp + (size_t)b * 3 * DHW + y * Wd + xx;
    float* uvb       = UV + (size_t)bc * DHW + y * Wd + xx;

    for (int d = 0; d < Dd; ++d) {
        float up0 = 0.f, up1 = 0.f, up2 = 0.f;
#pragma unroll
        for (int dk = 0; dk < 3; ++dk) {
            int zd = d + dk - 1; zd = zd < 0 ? 0 : (zd > Dd - 1 ? Dd - 1 : zd);
#pragma unroll
            for (int kh = 0; kh < 3; ++kh) {
                const float* row = &tile[zd][yr + kh][0];
                float v0 = row[xm], v1 = row[xx], v2 = row[xp];
                int k0 = (dk * 3 + kh) * 3;   // unfold order (dk,kh,kw)
                up0 += v0 * U_w[(k0+0)*3 + 0] + v1 * U_w[(k0+1)*3 + 0] + v2 * U_w[(k0+2)*3 + 0];
                up1 += v0 * U_w[(k0+0)*3 + 1] + v1 * U_w[(k0+1)*3 + 1] + v2 * U_w[(k0+2)*3 + 1];
                up2 += v0 * U_w[(k0+0)*3 + 2] + v1 * U_w[(k0+1)*3 + 2] + v2 * U_w[(k0+2)*3 + 2];
            }
        }
        float nrm = sqrtf(up0 * up0 + up1 * up1 + up2 * up2);
        float inv = 1.f / (1e-6f + nrm);
        float uv = (up0 * vpb[(size_t)d * HW]
                  + up1 * vpb[(size_t)DHW + d * HW]
                  + up2 * vpb[(size_t)2 * DHW + d * HW]) * inv;
        uvb[(size_t)d * HW] = uv;
    }
}

// ---------------------------------------------------------------------------
// Kernel 3: out = tail_w @ UV (1x1x1 conv over channels). Uniform CF so the
// weight rows scalarize to s_load.
// ---------------------------------------------------------------------------
__global__ __launch_bounds__(256) void k_tail(const float* __restrict__ UV,
                                              const float* __restrict__ tail_w,
                                              float* __restrict__ out)
{
    int p = blockIdx.x * 256 + threadIdx.x;   // grid exact: no guard
    int b = p >> 17;
    int s = p & (DHW - 1);

    const float* ub = UV + (size_t)b * Cn * DHW + s;
    float uv[Cn];
#pragma unroll
    for (int i = 0; i < Cn; ++i) uv[i] = ub[(size_t)i * DHW];

    float* ob = out + (size_t)b * Cn * DHW + s;
    for (int o = 0; o < Cn; ++o) {
        float a0 = 0.f, a1 = 0.f, a2 = 0.f, a3 = 0.f;
        const float* wr = tail_w + o * Cn;   // thread-uniform row -> s_load
#pragma unroll
        for (int i = 0; i < Cn; i += 4) {
            a0 += wr[i + 0] * uv[i + 0];
            a1 += wr[i + 1] * uv[i + 1];
            a2 += wr[i + 2] * uv[i + 2];
            a3 += wr[i + 3] * uv[i + 3];
        }
        ob[(size_t)o * DHW] = (a0 + a1) + (a2 + a3);
    }
}

extern "C" void kernel_launch(void* const* d_in, const int* in_sizes, int n_in,
                              void* d_out, int out_size, void* d_ws, size_t ws_size,
                              hipStream_t stream)
{
    const float* x      = (const float*)d_in[0];   // (2,64,8,128,128)
    const float* head_w = (const float*)d_in[1];   // (64,64)
    const float* tail_w = (const float*)d_in[2];   // (64,64)
    const float* U_w    = (const float*)d_in[3];   // (27,3)
    const float* V_w    = (const float*)d_in[4];   // (64,3)
    float* out = (float*)d_out;

    // Workspace layout: h (64MB) | UV (64MB) | Vp (3MB)
    float* h  = (float*)d_ws;
    float* UV = h + (size_t)NELEM;
    float* Vp = UV + (size_t)NELEM;

    k_head<<<NPOS / 256, 256, 0, stream>>>(x, head_w, V_w, h, Vp);
    k_uv<<<Bn * Cn * (Hd / 2), 256, 0, stream>>>(h, Vp, U_w, UV);
    k_tail<<<NPOS / 256, 256, 0, stream>>>(UV, tail_w, out);
}

// Round 5
// 267.234 us; speedup vs baseline: 1.2990x; 1.1944x over previous
//
#include <hip/hip_runtime.h>

#define Bn   2
#define Cn   64
#define Dd   8
#define Hd   128
#define Wd   128
#define HW   16384
#define DHW  131072     // 2^17
#define NPOS 262144     // 2^18
#define NELEM 16777216

typedef __attribute__((ext_vector_type(8))) short short8;
typedef __attribute__((ext_vector_type(4))) float floatx4;

__device__ __forceinline__ short f2bf(float f) {
    union { float f; unsigned u; } v; v.f = f;
    unsigned r = (v.u + 0x7FFFu + ((v.u >> 16) & 1u)) >> 16;   // RNE
    return (short)r;
}
__device__ __forceinline__ float bf2f(short s) {
    union { unsigned u; float f; } v; v.u = ((unsigned)(unsigned short)s) << 16;
    return v.f;
}

// ---------------------------------------------------------------------------
// k_prep: split-bf16 weights. Wh{h,l}[80][64]: rows 0..63 = head_w,
// rows 64..66 = V^T @ head_w (folds Vp), rows 67..79 = 0. Wt{h,l}[64][64].
// ---------------------------------------------------------------------------
__global__ __launch_bounds__(256) void k_prep(const float* __restrict__ head_w,
                                              const float* __restrict__ tail_w,
                                              const float* __restrict__ V_w,
                                              short* __restrict__ Whh, short* __restrict__ Whl,
                                              short* __restrict__ Wth, short* __restrict__ Wtl)
{
    int t = threadIdx.x;
#pragma unroll
    for (int rep = 0; rep < 16; ++rep) {
        int idx = rep * 256 + t;            // 4096
        float wh = head_w[idx];
        short hh = f2bf(wh);
        Whh[idx] = hh; Whl[idx] = f2bf(wh - bf2f(hh));
        float wt = tail_w[idx];
        short th = f2bf(wt);
        Wth[idx] = th; Wtl[idx] = f2bf(wt - bf2f(th));
    }
    if (t < 192) {                          // VW[r][i] = sum_c V[c][r]*W[c][i]
        int r = t >> 6, i = t & 63;
        float s = 0.f;
        for (int cc = 0; cc < 64; ++cc) s += V_w[cc * 3 + r] * head_w[cc * 64 + i];
        short hh = f2bf(s);
        Whh[(64 + r) * 64 + i] = hh;
        Whl[(64 + r) * 64 + i] = f2bf(s - bf2f(hh));
    }
#pragma unroll
    for (int rep = 0; rep < 4; ++rep) {     // zero rows 67..79 (832 entries)
        int idx = rep * 256 + t;
        if (idx < 832) { Whh[67 * 64 + idx] = 0; Whl[67 * 64 + idx] = 0; }
    }
}

// ---------------------------------------------------------------------------
// k_headm: [h | Vp] = Wh[80x64] @ x via split-bf16 MFMA (fp32-equivalent).
// Block = 128 positions. Fragment order in LDS: frag-block of 64 lanes x
// 8 shorts; slot = (quad<<4)|idx15, quad = (k&31)>>3, j = k&7.
// A: idx15 = pos&15 (m). B: idx15 = out&15 (n). D: m=(lane>>4)*4+reg, n=lane&15.
// ---------------------------------------------------------------------------
__global__ __launch_bounds__(256) void k_headm(const float* __restrict__ x,
                                               const short* __restrict__ Whh,
                                               const short* __restrict__ Whl,
                                               float* __restrict__ h,
                                               float* __restrict__ Vp)
{
    __shared__ short Xh[16 * 64 * 8], Xl[16 * 64 * 8];   // 16 KB each
    __shared__ short Bh[10 * 64 * 8], Bl[10 * 64 * 8];   // 10 KB each
    int t  = threadIdx.x;
    int p0 = blockIdx.x * 128;
    int b  = p0 >> 17;
    int s0 = p0 & (DHW - 1);
    const float* xb = x + ((size_t)b * Cn) * DHW + s0;

    int pp = t & 127;
    int ho = t >> 7;
#pragma unroll
    for (int pass = 0; pass < 4; ++pass) {
        int in0 = pass * 16 + ho * 8;
        short8 vh, vl;
#pragma unroll
        for (int j = 0; j < 8; ++j) {
            float f = xb[(size_t)(in0 + j) * DHW + pp];
            short hh = f2bf(f);
            vh[j] = hh; vl[j] = f2bf(f - bf2f(hh));
        }
        int blk  = ((in0 >> 5) << 3) | (pp >> 4);
        int slot = (((in0 >> 3) & 3) << 4) | (pp & 15);
        *(short8*)&Xh[(blk * 64 + slot) * 8] = vh;
        *(short8*)&Xl[(blk * 64 + slot) * 8] = vl;
    }
#pragma unroll
    for (int pass = 0; pass < 3; ++pass) {   // 640 16B-units of Wh
        int unit = pass * 256 + t;
        if (unit < 640) {
            int o   = unit - (unit / 80) * 80;
            int oc  = unit / 80;
            int in0 = oc * 8;
            int blk  = ((o >> 4) << 1) | (in0 >> 5);
            int slot = (((in0 >> 3) & 3) << 4) | (o & 15);
            *(short8*)&Bh[(blk * 64 + slot) * 8] = *(const short8*)&Whh[o * 64 + in0];
            *(short8*)&Bl[(blk * 64 + slot) * 8] = *(const short8*)&Whl[o * 64 + in0];
        }
    }
    __syncthreads();

    int lane = t & 63;
    int w    = t >> 6;
    floatx4 acc[2][5];
#pragma unroll
    for (int mt = 0; mt < 2; ++mt)
#pragma unroll
        for (int nt = 0; nt < 5; ++nt) acc[mt][nt] = (floatx4)0.f;

    const short8* XhV = (const short8*)Xh;
    const short8* XlV = (const short8*)Xl;
    const short8* BhV = (const short8*)Bh;
    const short8* BlV = (const short8*)Bl;
#pragma unroll
    for (int ks = 0; ks < 2; ++ks) {
        short8 ah0 = XhV[(ks * 8 + w * 2 + 0) * 64 + lane];
        short8 ah1 = XhV[(ks * 8 + w * 2 + 1) * 64 + lane];
        short8 al0 = XlV[(ks * 8 + w * 2 + 0) * 64 + lane];
        short8 al1 = XlV[(ks * 8 + w * 2 + 1) * 64 + lane];
#pragma unroll
        for (int nt = 0; nt < 5; ++nt) {
            short8 bh = BhV[(nt * 2 + ks) * 64 + lane];
            short8 bl = BlV[(nt * 2 + ks) * 64 + lane];
            acc[0][nt] = __builtin_amdgcn_mfma_f32_16x16x32_bf16(al0, bl, acc[0][nt], 0, 0, 0);
            acc[0][nt] = __builtin_amdgcn_mfma_f32_16x16x32_bf16(al0, bh, acc[0][nt], 0, 0, 0);
            acc[0][nt] = __builtin_amdgcn_mfma_f32_16x16x32_bf16(ah0, bl, acc[0][nt], 0, 0, 0);
            acc[0][nt] = __builtin_amdgcn_mfma_f32_16x16x32_bf16(ah0, bh, acc[0][nt], 0, 0, 0);
            acc[1][nt] = __builtin_amdgcn_mfma_f32_16x16x32_bf16(al1, bl, acc[1][nt], 0, 0, 0);
            acc[1][nt] = __builtin_amdgcn_mfma_f32_16x16x32_bf16(al1, bh, acc[1][nt], 0, 0, 0);
            acc[1][nt] = __builtin_amdgcn_mfma_f32_16x16x32_bf16(ah1, bl, acc[1][nt], 0, 0, 0);
            acc[1][nt] = __builtin_amdgcn_mfma_f32_16x16x32_bf16(ah1, bh, acc[1][nt], 0, 0, 0);
        }
    }

    int outc = lane & 15;
    int quad = lane >> 4;
#pragma unroll
    for (int mt = 0; mt < 2; ++mt) {
#pragma unroll
        for (int nt = 0; nt < 5; ++nt) {
            int o   = nt * 16 + outc;
            int pos = w * 32 + mt * 16 + quad * 4;
            if (o < 64) {
                *(floatx4*)&h[((size_t)(b * Cn + o)) * DHW + s0 + pos] = acc[mt][nt];
            } else if (o < 67) {
                *(floatx4*)&Vp[((size_t)(b * 3 + (o - 64))) * DHW + s0 + pos] = acc[mt][nt];
            }
        }
    }
}

// ---------------------------------------------------------------------------
// k_uv: fp32 depthwise 3x3x3 (replicate pad) -> l2norm over r -> dot Vp.
// Round-3-verified structure; float4-vectorized LDS staging.
// ---------------------------------------------------------------------------
__global__ __launch_bounds__(256) void k_uv(const float* __restrict__ h,
                                            const float* __restrict__ Vp,
                                            const float* __restrict__ U_w,
                                            float* __restrict__ UV)
{
    __shared__ float tile[Dd][4][Wd];   // 16 KB

    int blk = blockIdx.x;
    int yt  = blk & 63;
    int bc  = blk >> 6;                 // b*64 + c
    int b   = bc >> 6;
    int y0  = yt * 2;
    int t   = threadIdx.x;

    const float* hb = h + (size_t)bc * DHW;
#pragma unroll
    for (int rep = 0; rep < 4; ++rep) {   // 1024 float4 units
        int idx = rep * 256 + t;
        int d   = idx >> 7;
        int rem = idx & 127;
        int yr  = rem >> 5;
        int x4  = (rem & 31) * 4;
        int zy  = y0 - 1 + yr;
        zy = zy < 0 ? 0 : (zy > Hd - 1 ? Hd - 1 : zy);
        *(floatx4*)&tile[d][yr][x4] = *(const floatx4*)(hb + d * HW + zy * Wd + x4);
    }
    __syncthreads();

    int xx = t & 127;
    int yr = t >> 7;
    int y  = y0 + yr;
    int xm = xx - 1; if (xm < 0) xm = 0;
    int xp = xx + 1; if (xp > Wd - 1) xp = Wd - 1;

    const float* vpb = Vp + (size_t)b * 3 * DHW + y * Wd + xx;
    float* uvb       = UV + (size_t)bc * DHW + y * Wd + xx;

    for (int d = 0; d < Dd; ++d) {
        float up0 = 0.f, up1 = 0.f, up2 = 0.f;
#pragma unroll
        for (int dk = 0; dk < 3; ++dk) {
            int zd = d + dk - 1; zd = zd < 0 ? 0 : (zd > Dd - 1 ? Dd - 1 : zd);
#pragma unroll
            for (int kh = 0; kh < 3; ++kh) {
                const float* row = &tile[zd][yr + kh][0];
                float v0 = row[xm], v1 = row[xx], v2 = row[xp];
                int k0 = (dk * 3 + kh) * 3;   // unfold order (dk,kh,kw)
                up0 += v0 * U_w[(k0+0)*3 + 0] + v1 * U_w[(k0+1)*3 + 0] + v2 * U_w[(k0+2)*3 + 0];
                up1 += v0 * U_w[(k0+0)*3 + 1] + v1 * U_w[(k0+1)*3 + 1] + v2 * U_w[(k0+2)*3 + 1];
                up2 += v0 * U_w[(k0+0)*3 + 2] + v1 * U_w[(k0+1)*3 + 2] + v2 * U_w[(k0+2)*3 + 2];
            }
        }
        float nrm = sqrtf(up0 * up0 + up1 * up1 + up2 * up2);
        float inv = 1.f / (1e-6f + nrm);
        float uv = (up0 * vpb[(size_t)d * HW]
                  + up1 * vpb[(size_t)DHW + d * HW]
                  + up2 * vpb[(size_t)2 * DHW + d * HW]) * inv;
        uvb[(size_t)d * HW] = uv;
    }
}

// ---------------------------------------------------------------------------
// k_tailm: out = Wt[64x64] @ UV via split-bf16 MFMA (fp32-equivalent).
// ---------------------------------------------------------------------------
__global__ __launch_bounds__(256) void k_tailm(const float* __restrict__ UV,
                                               const short* __restrict__ Wth,
                                               const short* __restrict__ Wtl,
                                               float* __restrict__ out)
{
    __shared__ short Xh[16 * 64 * 8], Xl[16 * 64 * 8];   // 16 KB each
    __shared__ short Bh[8 * 64 * 8], Bl[8 * 64 * 8];     // 8 KB each
    int t  = threadIdx.x;
    int p0 = blockIdx.x * 128;
    int b  = p0 >> 17;
    int s0 = p0 & (DHW - 1);
    const float* ub = UV + ((size_t)b * Cn) * DHW + s0;

    int pp = t & 127;
    int ho = t >> 7;
#pragma unroll
    for (int pass = 0; pass < 4; ++pass) {
        int in0 = pass * 16 + ho * 8;
        short8 vh, vl;
#pragma unroll
        for (int j = 0; j < 8; ++j) {
            float f = ub[(size_t)(in0 + j) * DHW + pp];
            short hh = f2bf(f);
            vh[j] = hh; vl[j] = f2bf(f - bf2f(hh));
        }
        int blk  = ((in0 >> 5) << 3) | (pp >> 4);
        int slot = (((in0 >> 3) & 3) << 4) | (pp & 15);
        *(short8*)&Xh[(blk * 64 + slot) * 8] = vh;
        *(short8*)&Xl[(blk * 64 + slot) * 8] = vl;
    }
#pragma unroll
    for (int pass = 0; pass < 2; ++pass) {   // 512 16B-units of Wt
        int unit = pass * 256 + t;
        int o    = unit & 63;
        int oc   = unit >> 6;
        int in0  = oc * 8;
        int blk  = ((o >> 4) << 1) | (in0 >> 5);
        int slot = (((in0 >> 3) & 3) << 4) | (o & 15);
        *(short8*)&Bh[(blk * 64 + slot) * 8] = *(const short8*)&Wth[o * 64 + in0];
        *(short8*)&Bl[(blk * 64 + slot) * 8] = *(const short8*)&Wtl[o * 64 + in0];
    }
    __syncthreads();

    int lane = t & 63;
    int w    = t >> 6;
    floatx4 acc[2][4];
#pragma unroll
    for (int mt = 0; mt < 2; ++mt)
#pragma unroll
        for (int nt = 0; nt < 4; ++nt) acc[mt][nt] = (floatx4)0.f;

    const short8* XhV = (const short8*)Xh;
    const short8* XlV = (const short8*)Xl;
    const short8* BhV = (const short8*)Bh;
    const short8* BlV = (const short8*)Bl;
#pragma unroll
    for (int ks = 0; ks < 2; ++ks) {
        short8 ah0 = XhV[(ks * 8 + w * 2 + 0) * 64 + lane];
        short8 ah1 = XhV[(ks * 8 + w * 2 + 1) * 64 + lane];
        short8 al0 = XlV[(ks * 8 + w * 2 + 0) * 64 + lane];
        short8 al1 = XlV[(ks * 8 + w * 2 + 1) * 64 + lane];
#pragma unroll
        for (int nt = 0; nt < 4; ++nt) {
            short8 bh = BhV[(nt * 2 + ks) * 64 + lane];
            short8 bl = BlV[(nt * 2 + ks) * 64 + lane];
            acc[0][nt] = __builtin_amdgcn_mfma_f32_16x16x32_bf16(al0, bl, acc[0][nt], 0, 0, 0);
            acc[0][nt] = __builtin_amdgcn_mfma_f32_16x16x32_bf16(al0, bh, acc[0][nt], 0, 0, 0);
            acc[0][nt] = __builtin_amdgcn_mfma_f32_16x16x32_bf16(ah0, bl, acc[0][nt], 0, 0, 0);
            acc[0][nt] = __builtin_amdgcn_mfma_f32_16x16x32_bf16(ah0, bh, acc[0][nt], 0, 0, 0);
            acc[1][nt] = __builtin_amdgcn_mfma_f32_16x16x32_bf16(al1, bl, acc[1][nt], 0, 0, 0);
            acc[1][nt] = __builtin_amdgcn_mfma_f32_16x16x32_bf16(al1, bh, acc[1][nt], 0, 0, 0);
            acc[1][nt] = __builtin_amdgcn_mfma_f32_16x16x32_bf16(ah1, bl, acc[1][nt], 0, 0, 0);
            acc[1][nt] = __builtin_amdgcn_mfma_f32_16x16x32_bf16(ah1, bh, acc[1][nt], 0, 0, 0);
        }
    }

    int outc = lane & 15;
    int quad = lane >> 4;
#pragma unroll
    for (int mt = 0; mt < 2; ++mt) {
#pragma unroll
        for (int nt = 0; nt < 4; ++nt) {
            int o   = nt * 16 + outc;
            int pos = w * 32 + mt * 16 + quad * 4;
            *(floatx4*)&out[((size_t)(b * Cn + o)) * DHW + s0 + pos] = acc[mt][nt];
        }
    }
}

extern "C" void kernel_launch(void* const* d_in, const int* in_sizes, int n_in,
                              void* d_out, int out_size, void* d_ws, size_t ws_size,
                              hipStream_t stream)
{
    const float* x      = (const float*)d_in[0];
    const float* head_w = (const float*)d_in[1];
    const float* tail_w = (const float*)d_in[2];
    const float* U_w    = (const float*)d_in[3];
    const float* V_w    = (const float*)d_in[4];
    float* out = (float*)d_out;

    // ws: h fp32 (64MB) | Vp fp32 (3MB) | UV fp32 (64MB) | split weights
    float* h   = (float*)d_ws;
    float* Vp  = h + (size_t)NELEM;
    float* UVf = Vp + (size_t)Bn * 3 * DHW;
    short* Whh = (short*)(UVf + (size_t)NELEM);
    short* Whl = Whh + 80 * 64;
    short* Wth = Whl + 80 * 64;
    short* Wtl = Wth + 64 * 64;

    k_prep<<<1, 256, 0, stream>>>(head_w, tail_w, V_w, Whh, Whl, Wth, Wtl);
    k_headm<<<NPOS / 128, 256, 0, stream>>>(x, Whh, Whl, h, Vp);
    k_uv<<<Bn * Cn * (Hd / 2), 256, 0, stream>>>(h, Vp, U_w, UVf);
    k_tailm<<<NPOS / 128, 256, 0, stream>>>(UVf, Wth, Wtl, out);
}

// Round 6
// 233.514 us; speedup vs baseline: 1.4865x; 1.1444x over previous
//
#include <hip/hip_runtime.h>

#define Bn   2
#define Cn   64
#define Dd   8
#define Hd   128
#define Wd   128
#define HW   16384
#define DHW  131072     // 2^17
#define NPOS 262144     // 2^18
#define NELEM 16777216

typedef __attribute__((ext_vector_type(8))) short short8;
typedef __attribute__((ext_vector_type(4))) float floatx4;

__device__ __forceinline__ short f2bf(float f) {
    union { float f; unsigned u; } v; v.f = f;
    unsigned r = (v.u + 0x7FFFu + ((v.u >> 16) & 1u)) >> 16;   // RNE
    return (short)r;
}
__device__ __forceinline__ float bf2f(short s) {
    union { unsigned u; float f; } v; v.u = ((unsigned)(unsigned short)s) << 16;
    return v.f;
}
// Cheap truncation split: hi = upper16(f), lo = trunc16(f - hi). ~4 VALU ops.
// Pair error ~2^-17 relative — fp32-class for K=64 GEMMs.
__device__ __forceinline__ void split2(float f, short& hi, short& lo) {
    union { float f; unsigned u; } a; a.f = f;
    unsigned hu = a.u & 0xFFFF0000u;
    hi = (short)(hu >> 16);
    union { unsigned u; float f; } hb; hb.u = hu;
    union { float f; unsigned u; } lb; lb.f = f - hb.f;
    lo = (short)(lb.u >> 16);
}

// ---------------------------------------------------------------------------
// k_prep: split-bf16 weights. Wh{h,l}[80][64]: rows 0..63 = head_w,
// rows 64..66 = V^T @ head_w (folds Vp), rows 67..79 = 0. Wt{h,l}[64][64].
// ---------------------------------------------------------------------------
__global__ __launch_bounds__(256) void k_prep(const float* __restrict__ head_w,
                                              const float* __restrict__ tail_w,
                                              const float* __restrict__ V_w,
                                              short* __restrict__ Whh, short* __restrict__ Whl,
                                              short* __restrict__ Wth, short* __restrict__ Wtl)
{
    int t = threadIdx.x;
#pragma unroll
    for (int rep = 0; rep < 16; ++rep) {
        int idx = rep * 256 + t;            // 4096
        short hh, hl;
        split2(head_w[idx], hh, hl);
        Whh[idx] = hh; Whl[idx] = hl;
        split2(tail_w[idx], hh, hl);
        Wth[idx] = hh; Wtl[idx] = hl;
    }
    if (t < 192) {                          // VW[r][i] = sum_c V[c][r]*W[c][i]
        int r = t >> 6, i = t & 63;
        float s = 0.f;
        for (int cc = 0; cc < 64; ++cc) s += V_w[cc * 3 + r] * head_w[cc * 64 + i];
        short hh, hl;
        split2(s, hh, hl);
        Whh[(64 + r) * 64 + i] = hh;
        Whl[(64 + r) * 64 + i] = hl;
    }
#pragma unroll
    for (int rep = 0; rep < 4; ++rep) {     // zero rows 67..79 (832 entries)
        int idx = rep * 256 + t;
        if (idx < 832) { Whh[67 * 64 + idx] = 0; Whl[67 * 64 + idx] = 0; }
    }
}

// ---------------------------------------------------------------------------
// k_headm: [h | Vp] = Wh[80x64] @ x via split-bf16 MFMA (fp32-equivalent).
// Block = 128 positions. Fragment order in LDS; epilogue transposes C through
// LDS (row stride 132 floats, 16B-aligned, bank-optimal b128) so each global
// store instruction covers 2 rows x 512B contiguous.
// ---------------------------------------------------------------------------
__global__ __launch_bounds__(256) void k_headm(const float* __restrict__ x,
                                               const short* __restrict__ Whh,
                                               const short* __restrict__ Whl,
                                               float* __restrict__ h,
                                               float* __restrict__ Vp)
{
    __shared__ __align__(16) char smem[52 * 1024];
    short* Xh = (short*)smem;                    // 16 KB
    short* Xl = (short*)(smem + 16 * 1024);      // 16 KB
    short* Bh = (short*)(smem + 32 * 1024);      // 10 KB
    short* Bl = (short*)(smem + 42 * 1024);      // 10 KB
    float* Cb = (float*)smem;                    // epilogue: 80*132*4 = 42240 B

    int t  = threadIdx.x;
    int p0 = blockIdx.x * 128;
    int b  = p0 >> 17;
    int s0 = p0 & (DHW - 1);
    const float* xb = x + ((size_t)b * Cn) * DHW + s0;

    int pp = t & 127;
    int ho = t >> 7;
#pragma unroll
    for (int pass = 0; pass < 4; ++pass) {
        int in0 = pass * 16 + ho * 8;
        short8 vh, vl;
#pragma unroll
        for (int j = 0; j < 8; ++j) {
            short hh, hl;
            split2(xb[(size_t)(in0 + j) * DHW + pp], hh, hl);
            vh[j] = hh; vl[j] = hl;
        }
        int blk  = ((in0 >> 5) << 3) | (pp >> 4);
        int slot = (((in0 >> 3) & 3) << 4) | (pp & 15);
        *(short8*)&Xh[(blk * 64 + slot) * 8] = vh;
        *(short8*)&Xl[(blk * 64 + slot) * 8] = vl;
    }
#pragma unroll
    for (int pass = 0; pass < 3; ++pass) {   // 640 16B-units of Wh
        int unit = pass * 256 + t;
        if (unit < 640) {
            int o   = unit - (unit / 80) * 80;
            int oc  = unit / 80;
            int in0 = oc * 8;
            int blk  = ((o >> 4) << 1) | (in0 >> 5);
            int slot = (((in0 >> 3) & 3) << 4) | (o & 15);
            *(short8*)&Bh[(blk * 64 + slot) * 8] = *(const short8*)&Whh[o * 64 + in0];
            *(short8*)&Bl[(blk * 64 + slot) * 8] = *(const short8*)&Whl[o * 64 + in0];
        }
    }
    __syncthreads();

    int lane = t & 63;
    int w    = t >> 6;
    floatx4 acc[2][5];
#pragma unroll
    for (int mt = 0; mt < 2; ++mt)
#pragma unroll
        for (int nt = 0; nt < 5; ++nt) acc[mt][nt] = (floatx4)0.f;

    const short8* XhV = (const short8*)Xh;
    const short8* XlV = (const short8*)Xl;
    const short8* BhV = (const short8*)Bh;
    const short8* BlV = (const short8*)Bl;
#pragma unroll
    for (int ks = 0; ks < 2; ++ks) {
        short8 ah0 = XhV[(ks * 8 + w * 2 + 0) * 64 + lane];
        short8 ah1 = XhV[(ks * 8 + w * 2 + 1) * 64 + lane];
        short8 al0 = XlV[(ks * 8 + w * 2 + 0) * 64 + lane];
        short8 al1 = XlV[(ks * 8 + w * 2 + 1) * 64 + lane];
#pragma unroll
        for (int nt = 0; nt < 5; ++nt) {
            short8 bh = BhV[(nt * 2 + ks) * 64 + lane];
            short8 bl = BlV[(nt * 2 + ks) * 64 + lane];
            acc[0][nt] = __builtin_amdgcn_mfma_f32_16x16x32_bf16(al0, bl, acc[0][nt], 0, 0, 0);
            acc[0][nt] = __builtin_amdgcn_mfma_f32_16x16x32_bf16(al0, bh, acc[0][nt], 0, 0, 0);
            acc[0][nt] = __builtin_amdgcn_mfma_f32_16x16x32_bf16(ah0, bl, acc[0][nt], 0, 0, 0);
            acc[0][nt] = __builtin_amdgcn_mfma_f32_16x16x32_bf16(ah0, bh, acc[0][nt], 0, 0, 0);
            acc[1][nt] = __builtin_amdgcn_mfma_f32_16x16x32_bf16(al1, bl, acc[1][nt], 0, 0, 0);
            acc[1][nt] = __builtin_amdgcn_mfma_f32_16x16x32_bf16(al1, bh, acc[1][nt], 0, 0, 0);
            acc[1][nt] = __builtin_amdgcn_mfma_f32_16x16x32_bf16(ah1, bl, acc[1][nt], 0, 0, 0);
            acc[1][nt] = __builtin_amdgcn_mfma_f32_16x16x32_bf16(ah1, bh, acc[1][nt], 0, 0, 0);
        }
    }

    __syncthreads();                        // frag reads done; reuse LDS as Cb
    int outc = lane & 15;
    int quad = lane >> 4;
#pragma unroll
    for (int mt = 0; mt < 2; ++mt)
#pragma unroll
        for (int nt = 0; nt < 5; ++nt) {
            int o   = nt * 16 + outc;
            int pos = w * 32 + mt * 16 + quad * 4;
            *(floatx4*)&Cb[o * 132 + pos] = acc[mt][nt];
        }
    __syncthreads();

    int xr = (t & 31) * 4;                  // 0..124
    int ob = t >> 5;                        // 0..7
#pragma unroll
    for (int pass = 0; pass < 9; ++pass) {
        int o = pass * 8 + ob;
        floatx4 vv = *(const floatx4*)&Cb[o * 132 + xr];
        if (o < 64) {
            *(floatx4*)&h[((size_t)(b * Cn + o)) * DHW + s0 + xr] = vv;
        } else if (o < 67) {
            *(floatx4*)&Vp[((size_t)(b * 3 + (o - 64))) * DHW + s0 + xr] = vv;
        }
    }
}

// ---------------------------------------------------------------------------
// k_uv: fp32 depthwise 3x3x3 (replicate pad) -> l2norm over r -> dot Vp.
// Slice-major register schedule: each of 8 LDS slices is read ONCE (9 values)
// and contributed to the <=3 outputs it feeds (72 ds_reads vs 216).
// ---------------------------------------------------------------------------
__global__ __launch_bounds__(256) void k_uv(const float* __restrict__ h,
                                            const float* __restrict__ Vp,
                                            const float* __restrict__ U_w,
                                            float* __restrict__ UV)
{
    __shared__ float tile[Dd][4][Wd];   // 16 KB

    int blk = blockIdx.x;
    int yt  = blk & 63;
    int bc  = blk >> 6;                 // b*64 + c
    int b   = bc >> 6;
    int y0  = yt * 2;
    int t   = threadIdx.x;

    const float* hb = h + (size_t)bc * DHW;
#pragma unroll
    for (int rep = 0; rep < 4; ++rep) {   // 1024 float4 units
        int idx = rep * 256 + t;
        int d   = idx >> 7;
        int rem = idx & 127;
        int yr  = rem >> 5;
        int x4  = (rem & 31) * 4;
        int zy  = y0 - 1 + yr;
        zy = zy < 0 ? 0 : (zy > Hd - 1 ? Hd - 1 : zy);
        *(floatx4*)&tile[d][yr][x4] = *(const floatx4*)(hb + d * HW + zy * Wd + x4);
    }
    __syncthreads();

    int xx = t & 127;
    int yr = t >> 7;
    int y  = y0 + yr;
    int xm = xx - 1; if (xm < 0) xm = 0;
    int xp = xx + 1; if (xp > Wd - 1) xp = Wd - 1;

    float a0[8], a1[8], a2[8];
#pragma unroll
    for (int d = 0; d < 8; ++d) { a0[d] = 0.f; a1[d] = 0.f; a2[d] = 0.f; }

#define CONTRIB(dd, dk)                                                   \
    {                                                                     \
        _Pragma("unroll")                                                 \
        for (int kh = 0; kh < 3; ++kh) {                                  \
            _Pragma("unroll")                                             \
            for (int kw = 0; kw < 3; ++kw) {                              \
                const int kk = (((dk) * 3 + kh) * 3 + kw) * 3;            \
                a0[dd] += v[kh][kw] * U_w[kk + 0];                        \
                a1[dd] += v[kh][kw] * U_w[kk + 1];                        \
                a2[dd] += v[kh][kw] * U_w[kk + 2];                        \
            }                                                             \
        }                                                                 \
    }

#pragma unroll
    for (int sl = 0; sl < 8; ++sl) {
        float v[3][3];
#pragma unroll
        for (int kh = 0; kh < 3; ++kh) {
            const float* row = &tile[sl][yr + kh][0];
            v[kh][0] = row[xm]; v[kh][1] = row[xx]; v[kh][2] = row[xp];
        }
        CONTRIB(sl, 1);                         // dk=1 -> d = sl
        if (sl == 0) CONTRIB(0, 0);             // replicate clamp low
        if (sl < 7)  CONTRIB(sl + 1, 0);        // dk=0 -> d = sl+1
        if (sl > 0)  CONTRIB(sl - 1, 2);        // dk=2 -> d = sl-1
        if (sl == 7) CONTRIB(7, 2);             // replicate clamp high
    }
#undef CONTRIB

    const float* vpb = Vp + (size_t)b * 3 * DHW + y * Wd + xx;
    float* uvb       = UV + (size_t)bc * DHW + y * Wd + xx;
#pragma unroll
    for (int d = 0; d < 8; ++d) {
        float nrm = sqrtf(a0[d] * a0[d] + a1[d] * a1[d] + a2[d] * a2[d]);
        float inv = 1.f / (1e-6f + nrm);
        float uv = (a0[d] * vpb[(size_t)d * HW]
                  + a1[d] * vpb[(size_t)DHW + d * HW]
                  + a2[d] * vpb[(size_t)2 * DHW + d * HW]) * inv;
        uvb[(size_t)d * HW] = uv;
    }
}

// ---------------------------------------------------------------------------
// k_tailm: out = Wt[64x64] @ UV via split-bf16 MFMA, LDS-transposed epilogue.
// ---------------------------------------------------------------------------
__global__ __launch_bounds__(256) void k_tailm(const float* __restrict__ UV,
                                               const short* __restrict__ Wth,
                                               const short* __restrict__ Wtl,
                                               float* __restrict__ out)
{
    __shared__ __align__(16) char smem[48 * 1024];
    short* Xh = (short*)smem;                    // 16 KB
    short* Xl = (short*)(smem + 16 * 1024);      // 16 KB
    short* Bh = (short*)(smem + 32 * 1024);      // 8 KB
    short* Bl = (short*)(smem + 40 * 1024);      // 8 KB
    float* Cb = (float*)smem;                    // 64*132*4 = 33792 B

    int t  = threadIdx.x;
    int p0 = blockIdx.x * 128;
    int b  = p0 >> 17;
    int s0 = p0 & (DHW - 1);
    const float* ub = UV + ((size_t)b * Cn) * DHW + s0;

    int pp = t & 127;
    int ho = t >> 7;
#pragma unroll
    for (int pass = 0; pass < 4; ++pass) {
        int in0 = pass * 16 + ho * 8;
        short8 vh, vl;
#pragma unroll
        for (int j = 0; j < 8; ++j) {
            short hh, hl;
            split2(ub[(size_t)(in0 + j) * DHW + pp], hh, hl);
            vh[j] = hh; vl[j] = hl;
        }
        int blk  = ((in0 >> 5) << 3) | (pp >> 4);
        int slot = (((in0 >> 3) & 3) << 4) | (pp & 15);
        *(short8*)&Xh[(blk * 64 + slot) * 8] = vh;
        *(short8*)&Xl[(blk * 64 + slot) * 8] = vl;
    }
#pragma unroll
    for (int pass = 0; pass < 2; ++pass) {   // 512 16B-units of Wt
        int unit = pass * 256 + t;
        int o    = unit & 63;
        int oc   = unit >> 6;
        int in0  = oc * 8;
        int blk  = ((o >> 4) << 1) | (in0 >> 5);
        int slot = (((in0 >> 3) & 3) << 4) | (o & 15);
        *(short8*)&Bh[(blk * 64 + slot) * 8] = *(const short8*)&Wth[o * 64 + in0];
        *(short8*)&Bl[(blk * 64 + slot) * 8] = *(const short8*)&Wtl[o * 64 + in0];
    }
    __syncthreads();

    int lane = t & 63;
    int w    = t >> 6;
    floatx4 acc[2][4];
#pragma unroll
    for (int mt = 0; mt < 2; ++mt)
#pragma unroll
        for (int nt = 0; nt < 4; ++nt) acc[mt][nt] = (floatx4)0.f;

    const short8* XhV = (const short8*)Xh;
    const short8* XlV = (const short8*)Xl;
    const short8* BhV = (const short8*)Bh;
    const short8* BlV = (const short8*)Bl;
#pragma unroll
    for (int ks = 0; ks < 2; ++ks) {
        short8 ah0 = XhV[(ks * 8 + w * 2 + 0) * 64 + lane];
        short8 ah1 = XhV[(ks * 8 + w * 2 + 1) * 64 + lane];
        short8 al0 = XlV[(ks * 8 + w * 2 + 0) * 64 + lane];
        short8 al1 = XlV[(ks * 8 + w * 2 + 1) * 64 + lane];
#pragma unroll
        for (int nt = 0; nt < 4; ++nt) {
            short8 bh = BhV[(nt * 2 + ks) * 64 + lane];
            short8 bl = BlV[(nt * 2 + ks) * 64 + lane];
            acc[0][nt] = __builtin_amdgcn_mfma_f32_16x16x32_bf16(al0, bl, acc[0][nt], 0, 0, 0);
            acc[0][nt] = __builtin_amdgcn_mfma_f32_16x16x32_bf16(al0, bh, acc[0][nt], 0, 0, 0);
            acc[0][nt] = __builtin_amdgcn_mfma_f32_16x16x32_bf16(ah0, bl, acc[0][nt], 0, 0, 0);
            acc[0][nt] = __builtin_amdgcn_mfma_f32_16x16x32_bf16(ah0, bh, acc[0][nt], 0, 0, 0);
            acc[1][nt] = __builtin_amdgcn_mfma_f32_16x16x32_bf16(al1, bl, acc[1][nt], 0, 0, 0);
            acc[1][nt] = __builtin_amdgcn_mfma_f32_16x16x32_bf16(al1, bh, acc[1][nt], 0, 0, 0);
            acc[1][nt] = __builtin_amdgcn_mfma_f32_16x16x32_bf16(ah1, bl, acc[1][nt], 0, 0, 0);
            acc[1][nt] = __builtin_amdgcn_mfma_f32_16x16x32_bf16(ah1, bh, acc[1][nt], 0, 0, 0);
        }
    }

    __syncthreads();
    int outc = lane & 15;
    int quad = lane >> 4;
#pragma unroll
    for (int mt = 0; mt < 2; ++mt)
#pragma unroll
        for (int nt = 0; nt < 4; ++nt) {
            int o   = nt * 16 + outc;
            int pos = w * 32 + mt * 16 + quad * 4;
            *(floatx4*)&Cb[o * 132 + pos] = acc[mt][nt];
        }
    __syncthreads();

    int xr = (t & 31) * 4;
    int ob = t >> 5;
#pragma unroll
    for (int pass = 0; pass < 8; ++pass) {
        int o = pass * 8 + ob;
        floatx4 vv = *(const floatx4*)&Cb[o * 132 + xr];
        *(floatx4*)&out[((size_t)(b * Cn + o)) * DHW + s0 + xr] = vv;
    }
}

extern "C" void kernel_launch(void* const* d_in, const int* in_sizes, int n_in,
                              void* d_out, int out_size, void* d_ws, size_t ws_size,
                              hipStream_t stream)
{
    const float* x      = (const float*)d_in[0];
    const float* head_w = (const float*)d_in[1];
    const float* tail_w = (const float*)d_in[2];
    const float* U_w    = (const float*)d_in[3];
    const float* V_w    = (const float*)d_in[4];
    float* out = (float*)d_out;

    // ws: h fp32 (64MB) | Vp fp32 (3MB) | UV fp32 (64MB) | split weights
    float* h   = (float*)d_ws;
    float* Vp  = h + (size_t)NELEM;
    float* UVf = Vp + (size_t)Bn * 3 * DHW;
    short* Whh = (short*)(UVf + (size_t)NELEM);
    short* Whl = Whh + 80 * 64;
    short* Wth = Whl + 80 * 64;
    short* Wtl = Wth + 64 * 64;

    k_prep<<<1, 256, 0, stream>>>(head_w, tail_w, V_w, Whh, Whl, Wth, Wtl);
    k_headm<<<NPOS / 128, 256, 0, stream>>>(x, Whh, Whl, h, Vp);
    k_uv<<<Bn * Cn * (Hd / 2), 256, 0, stream>>>(h, Vp, U_w, UVf);
    k_tailm<<<NPOS / 128, 256, 0, stream>>>(UVf, Wth, Wtl, out);
}